// Round 5
// baseline (212.454 us; speedup 1.0000x reference)
//
#include <hip/hip_runtime.h>

// SimpleSAGE: 2-layer mean-SAGE + center-node readout, frontier-pruned.
// Only 500 center nodes are read at the output; only their 1-hop sources
// (~8.5k nodes) need layer-1 features. We scan the edge list to build the
// frontier, aggregate only into flagged destinations, and run the small
// 64x64 GEMVs one wave per node.

constexpr int NN  = 50000;   // nodes
constexpr int NG  = 500;     // graphs
constexpr int NPG = 100;     // nodes per graph
constexpr int NE  = 800000;  // edges
constexpr int D   = 64;      // feature dim

// ---- workspace layout (all zero-initialized by one memset) ----
// agg1 : NN*D floats   (layer-1 mean numerator, then overwritten in-place with h1)
// agg2 : NG*D floats   (layer-2 mean numerator for the center of each graph)
// deg  : NN ints       (full in-degree)
// flag : NN ints       (bit0 = center node, bit1 = needs h1)

__global__ void k_init(const int* __restrict__ cpos, int* __restrict__ flag) {
  int g = blockIdx.x * blockDim.x + threadIdx.x;
  if (g < NG) {
    int c = g * NPG + cpos[g];
    flag[c] = 3;  // center + needs h1
  }
}

__global__ void k_mark(const int* __restrict__ src, const int* __restrict__ dst,
                       int* __restrict__ flag, int* __restrict__ deg) {
  int stride = gridDim.x * blockDim.x;
  for (int e = blockIdx.x * blockDim.x + threadIdx.x; e < NE; e += stride) {
    int d = dst[e];
    atomicAdd(&deg[d], 1);               // full in-degree (mean denominator)
    if (flag[d] & 1) atomicOr(&flag[src[e]], 2);  // src feeds a center -> needs h1
  }
}

// Aggregate feat[src] into agg[...] for edges whose dst has flag bit BIT set.
// Wave-cooperative: each wave scans 64 edges, ballots the matches, then all
// 64 lanes cooperatively gather/atomic one matching edge at a time (coalesced
// 256B gather + coalesced 64-lane atomicAdd).
template <int BIT>
__global__ void k_agg(const int* __restrict__ src, const int* __restrict__ dst,
                      const int* __restrict__ flag, const float* __restrict__ feat,
                      float* __restrict__ agg) {
  int lane = threadIdx.x & 63;
  int wid  = (blockIdx.x * blockDim.x + threadIdx.x) >> 6;
  int nw   = (gridDim.x * blockDim.x) >> 6;
  for (int base = wid * 64; base < NE; base += nw * 64) {
    int e = base + lane;            // NE % 64 == 0 -> wave-uniform validity
    int s = 0, d = 0;
    bool m = false;
    if (e < NE) {
      d = dst[e];
      m = (flag[d] & BIT) != 0;
      if (m) s = src[e];
    }
    unsigned long long bal = __ballot(m);
    while (bal) {
      int b = __ffsll(bal) - 1;
      bal &= bal - 1;
      int sd = __shfl(s, b);
      int dd = __shfl(d, b);
      float v = feat[sd * D + lane];
      if (BIT == 1)
        atomicAdd(&agg[(dd / NPG) * D + lane], v);   // index by graph id
      else
        atomicAdd(&agg[dd * D + lane], v);
    }
  }
}

// h1[v] = relu(Wl1 * (agg1[v]/max(deg,1)) + bl1 + Wr1 * x[v]), in-place in agg1.
// One wave per flagged node; weights staged in LDS with +1 row padding
// (row stride 65 -> bank (lane+k)%32, conflict-free 2-way).
__global__ void k_sage1(const float* __restrict__ x, const int* __restrict__ flag,
                        const int* __restrict__ deg, float* __restrict__ agg1,
                        const float* __restrict__ Wl, const float* __restrict__ bl,
                        const float* __restrict__ Wr) {
  __shared__ float sWl[D * 65];
  __shared__ float sWr[D * 65];
  __shared__ float sbl[D];
  int tid = threadIdx.x;
  for (int i = tid; i < D * D; i += blockDim.x) {
    int r = i >> 6, c = i & 63;
    sWl[r * 65 + c] = Wl[i];
    sWr[r * 65 + c] = Wr[i];
  }
  if (tid < D) sbl[tid] = bl[tid];
  __syncthreads();

  int lane = tid & 63;
  int wid  = (blockIdx.x * blockDim.x + tid) >> 6;
  int nw   = (gridDim.x * blockDim.x) >> 6;
  for (int v = wid; v < NN; v += nw) {
    if (!(flag[v] & 2)) continue;           // wave-uniform (same v per wave)
    float dg = (float)deg[v];
    if (dg < 1.f) dg = 1.f;
    float m  = agg1[v * D + lane] / dg;
    float xv = x[v * D + lane];
    float h  = sbl[lane];
#pragma unroll
    for (int k = 0; k < D; k++) {
      float mk = __shfl(m, k);
      float xk = __shfl(xv, k);
      h += sWl[lane * 65 + k] * mk + sWr[lane * 65 + k] * xk;
    }
    agg1[v * D + lane] = fmaxf(h, 0.f);     // h1 in-place
  }
}

// Per graph: h2 = relu(Wl2*(agg2[g]/deg[c]) + bl2 + Wr2*h1[c]); out = Wlin.h2 + blin
__global__ void k_final(const float* __restrict__ h1, const float* __restrict__ agg2,
                        const int* __restrict__ deg, const int* __restrict__ cpos,
                        const float* __restrict__ Wl2, const float* __restrict__ bl2,
                        const float* __restrict__ Wr2, const float* __restrict__ Wlin,
                        const float* __restrict__ blin, float* __restrict__ out) {
  int lane = threadIdx.x & 63;
  int g = (blockIdx.x * blockDim.x + threadIdx.x) >> 6;
  if (g >= NG) return;
  int c = g * NPG + cpos[g];
  float dg = (float)deg[c];
  if (dg < 1.f) dg = 1.f;
  float m  = agg2[g * D + lane] / dg;
  float hc = h1[c * D + lane];
  float h  = bl2[lane];
#pragma unroll
  for (int k = 0; k < D; k++) {
    h += Wl2[lane * D + k] * __shfl(m, k) + Wr2[lane * D + k] * __shfl(hc, k);
  }
  h = fmaxf(h, 0.f);
  float p = Wlin[lane] * h;
#pragma unroll
  for (int off = 32; off; off >>= 1) p += __shfl_down(p, off);
  if (lane == 0) out[g] = p + blin[0];
}

extern "C" void kernel_launch(void* const* d_in, const int* in_sizes, int n_in,
                              void* d_out, int out_size, void* d_ws, size_t ws_size,
                              hipStream_t stream) {
  const float* x    = (const float*)d_in[0];
  const int*   ei   = (const int*)d_in[1];
  const int*   srcI = ei;          // edge_index[0]
  const int*   dstI = ei + NE;     // edge_index[1]
  const int*   cpos = (const int*)d_in[3];
  const float* Wl1  = (const float*)d_in[4];
  const float* bl1  = (const float*)d_in[5];
  const float* Wr1  = (const float*)d_in[6];
  const float* Wl2  = (const float*)d_in[7];
  const float* bl2  = (const float*)d_in[8];
  const float* Wr2  = (const float*)d_in[9];
  const float* Wlin = (const float*)d_in[10];
  const float* blin = (const float*)d_in[11];
  float* out = (float*)d_out;

  char* ws = (char*)d_ws;
  float* agg1 = (float*)ws;                                      // NN*D
  float* agg2 = (float*)(ws + (size_t)NN * D * 4);               // NG*D
  int*   deg  = (int*)(ws + (size_t)NN * D * 4 + (size_t)NG * D * 4);
  int*   flag = deg + NN;
  size_t total = (size_t)NN * D * 4 + (size_t)NG * D * 4 + (size_t)NN * 4 * 2;

  hipMemsetAsync(d_ws, 0, total, stream);
  k_init<<<2, 256, 0, stream>>>(cpos, flag);
  k_mark<<<2048, 256, 0, stream>>>(srcI, dstI, flag, deg);
  k_agg<2><<<2048, 256, 0, stream>>>(srcI, dstI, flag, x, agg1);
  k_sage1<<<1024, 256, 0, stream>>>(x, flag, deg, agg1, Wl1, bl1, Wr1);
  k_agg<1><<<2048, 256, 0, stream>>>(srcI, dstI, flag, agg1, agg2);
  k_final<<<(NG * 64 + 255) / 256, 256, 0, stream>>>(agg1, agg2, deg, cpos,
                                                     Wl2, bl2, Wr2, Wlin, blin, out);
}